// Round 10
// baseline (259.197 us; speedup 1.0000x reference)
//
#include <hip/hip_runtime.h>
#include <cmath>

#define NPTS 262144
#define NLVL 16
#define TBL  524288u
#define TMASK 524287u
#define TPB  128   // points per block (k2)
#define NQ   7     // levels 0..6 densified (0..5 oct, 6 quad)

typedef __attribute__((ext_vector_type(8))) short short8;
typedef __attribute__((ext_vector_type(4))) float f32x4;

struct ResArr { float r[NLVL]; };
struct QuadInfo { int off[NQ]; int dim[NQ]; };   // off in uint4 units

__device__ __forceinline__ unsigned short f2bf(float f) {
    union { float f; unsigned u; } v; v.f = f;
    unsigned r = v.u + 0x7FFFu + ((v.u >> 16) & 1u);   // RNE
    return (unsigned short)(r >> 16);
}
__device__ __forceinline__ float blo(unsigned u) {
    union { unsigned v; float f; } x; x.v = u << 16; return x.f;
}
__device__ __forceinline__ float bhi(unsigned u) {
    union { unsigned v; float f; } x; x.v = u & 0xffff0000u; return x.f;
}
__device__ __forceinline__ unsigned packbf(float a, float b) {
    return (unsigned)f2bf(a) | ((unsigned)f2bf(b) << 16);
}

#define MFMA(a,b,c) __builtin_amdgcn_mfma_f32_16x16x32_bf16((a),(b),(c),0,0,0)

// ---------------------------------------------------------------------------
// Prep kernel: blockIdx.y = level 0..5 -> oct arrays (both x-slabs, 32B/cell,
// 1 merged L2 request per point later); y==6 -> quad array for l6;
// y==7, block 0 -> pack MLP weights+biases.
// ---------------------------------------------------------------------------
__global__ __launch_bounds__(256) void prep_k(
    const float* __restrict__ emb,
    uint4* __restrict__ octq, QuadInfo qi,
    const float* __restrict__ dw1, const float* __restrict__ db1,
    const float* __restrict__ dw2, const float* __restrict__ db2,
    const float* __restrict__ cw1, const float* __restrict__ cb1,
    const float* __restrict__ cw2, const float* __restrict__ cb2,
    const float* __restrict__ cw3, const float* __restrict__ cb3,
    const float* __restrict__ cw4, const float* __restrict__ cb4,
    unsigned short* __restrict__ wpk, float* __restrict__ bpk)
{
    const int l = blockIdx.y;
    const int tid = threadIdx.x;

    if (l == 7) {
        if (blockIdx.x != 0) return;
        // ---- weight pack (bf16 B-fragments, 16x16x32 layout) ----
        const int wid  = tid >> 6;
        const int lane = tid & 63;
        const int m16  = lane & 15;
        const int q    = lane >> 4;
        const unsigned char MAT[28] = {0,0,0,0, 1,1, 2,2,2,2, 3,3,3,3,3,3,3,3, 4,4,4,4,4,4,4,4, 5,5};
        const unsigned char K0 [28] = {0,0,0,0, 0,32, 0,0,0,0, 0,0,0,0,32,32,32,32, 0,0,0,0,32,32,32,32, 0,32};
        const unsigned char N0 [28] = {0,16,32,48, 0,0, 0,16,32,48, 0,16,32,48,0,16,32,48, 0,16,32,48,0,16,32,48, 0,0};
        #pragma unroll
        for (int s = 0; s < 28; ++s) {
            if ((s & 3) == wid) {
                const int mat = MAT[s];
                const float* src = mat==0?dw1 : mat==1?dw2 : mat==2?cw1 : mat==3?cw2 : mat==4?cw3 : cw4;
                const int fan = (mat==1) ? 16 : (mat==5) ? 3 : 64;
                const int k = (int)K0[s] + q*8;
                const int n = (int)N0[s] + m16;
                unsigned short u[8];
                #pragma unroll
                for (int j = 0; j < 8; ++j) {
                    float v = 0.f;
                    if (mat != 5 || n < 3) v = src[(k+j)*fan + n];
                    u[j] = f2bf(v);
                }
                unsigned* w32 = (unsigned*)(wpk + s*512 + lane*8);
                w32[0] = (unsigned)u[0] | ((unsigned)u[1] << 16);
                w32[1] = (unsigned)u[2] | ((unsigned)u[3] << 16);
                w32[2] = (unsigned)u[4] | ((unsigned)u[5] << 16);
                w32[3] = (unsigned)u[6] | ((unsigned)u[7] << 16);
            }
        }
        {
            int t = tid;
            if      (t <  64) bpk[t] = db1[t];
            else if (t <  80) bpk[t] = db2[t-64];
            else if (t < 144) bpk[t] = cb1[t-80];
            else if (t < 208) bpk[t] = cb2[t-144];
        }
        if (tid < 80) {
            int t = tid + 208;
            if (t < 272) bpk[t] = cb3[t-208];
            else         bpk[t] = (t-272 < 3) ? cb4[t-272] : 0.f;
        }
        return;
    }

    const int t = blockIdx.x * 256 + tid;
    const int D = qi.dim[l];
    if (t >= D*D*D) return;
    const unsigned z = (unsigned)t % (unsigned)D;
    const unsigned rem = (unsigned)t / (unsigned)D;
    const unsigned y = rem % (unsigned)D;
    const unsigned x = rem / (unsigned)D;

    const float2* __restrict__ emb2 = (const float2*)emb;
    const unsigned base = (unsigned)l * TBL;
    const unsigned hy0 = y*2654435761u, hy1 = (y+1u)*2654435761u;
    const unsigned hz0 = z*805459861u,  hz1 = (z+1u)*805459861u;

    const float2 a0 = emb2[base + ((x^hy0^hz0)&TMASK)];
    const float2 b0 = emb2[base + ((x^hy0^hz1)&TMASK)];
    const float2 c0 = emb2[base + ((x^hy1^hz0)&TMASK)];
    const float2 d0 = emb2[base + ((x^hy1^hz1)&TMASK)];
    uint4 qa;
    qa.x = packbf(a0.x, a0.y);
    qa.y = packbf(b0.x, b0.y);
    qa.z = packbf(c0.x, c0.y);
    qa.w = packbf(d0.x, d0.y);

    if (l < 6) {
        const unsigned x1 = x + 1u;
        const float2 a1 = emb2[base + ((x1^hy0^hz0)&TMASK)];
        const float2 b1 = emb2[base + ((x1^hy0^hz1)&TMASK)];
        const float2 c1 = emb2[base + ((x1^hy1^hz0)&TMASK)];
        const float2 d1 = emb2[base + ((x1^hy1^hz1)&TMASK)];
        uint4 qb;
        qb.x = packbf(a1.x, a1.y);
        qb.y = packbf(b1.x, b1.y);
        qb.z = packbf(c1.x, c1.y);
        qb.w = packbf(d1.x, d1.y);
        octq[qi.off[l] + 2*t]     = qa;
        octq[qi.off[l] + 2*t + 1] = qb;
    } else {
        octq[qi.off[6] + t] = qa;
    }
}

// ---------------------------------------------------------------------------
// Kernel 1: hash-grid encode, cost-balanced XCD schedule.
// grid = 11008 blocks; xcd = b&7, s = b>>3 in [0,1376).
//  s < 1024        : hashed level (7+xcd), point chunk s           (2.1M/XCD)
//  1024 <= s <1152 : l15 eighth                                    (0.26M/XCD)
//  s >= 1152       : g = xcd*224 + (s-1152) in [0,1792): l=g>>8, c=g&255
//                    l<6: oct (1 merged req/pt), l==6: quad (2/pt) (0.26M/XCD)
// ---------------------------------------------------------------------------
__global__ __launch_bounds__(256) void hash_encode_k(
    const float* __restrict__ coords,
    const float* __restrict__ emb,
    const uint4* __restrict__ octq,
    unsigned* __restrict__ featws,
    ResArr res, QuadInfo qi)
{
    const int tid = threadIdx.x;
    const int b   = blockIdx.x;
    const int xcd = b & 7;
    const int s   = b >> 3;

    if (s < 1152) {
        // -------- hashed path --------
        int l, p;
        if (s < 1024) {
            l = 7 + xcd;
            p = s * 256 + tid;
        } else {
            l = 15;
            p = xcd * 32768 + (s - 1024) * 256 + tid;
        }

        const float cx = coords[3*p], cy = coords[3*p+1], cz = coords[3*p+2];
        const float r = res.r[l];
        const float px = cx*r, py = cy*r, pz = cz*r;
        const float fpx = floorf(px), fpy = floorf(py), fpz = floorf(pz);
        const float fx = px-fpx, fy = py-fpy, fz = pz-fpz;
        const unsigned ix=(unsigned)fpx, iy=(unsigned)fpy, iz=(unsigned)fpz;
        const unsigned hx0=ix,             hx1=ix+1u;
        const unsigned hy0=iy*2654435761u, hy1=(iy+1u)*2654435761u;
        const unsigned hz0=iz*805459861u,  hz1=(iz+1u)*805459861u;
        const unsigned base = (unsigned)l * TBL;
        const float2* __restrict__ emb2 = (const float2*)emb;

        const float2 f000 = emb2[base + ((hx0^hy0^hz0)&TMASK)];
        const float2 f001 = emb2[base + ((hx0^hy0^hz1)&TMASK)];
        const float2 f010 = emb2[base + ((hx0^hy1^hz0)&TMASK)];
        const float2 f011 = emb2[base + ((hx0^hy1^hz1)&TMASK)];
        const float2 f100 = emb2[base + ((hx1^hy0^hz0)&TMASK)];
        const float2 f101 = emb2[base + ((hx1^hy0^hz1)&TMASK)];
        const float2 f110 = emb2[base + ((hx1^hy1^hz0)&TMASK)];
        const float2 f111 = emb2[base + ((hx1^hy1^hz1)&TMASK)];

        const float wx0=1.f-fx, wy0=1.f-fy, wz0=1.f-fz;
        float o0, o1;
        o0 = wx0*wy0*wz0*f000.x;                 o1 = wx0*wy0*wz0*f000.y;
        o0 = fmaf(wx0*wy0*fz,  f001.x, o0);      o1 = fmaf(wx0*wy0*fz,  f001.y, o1);
        o0 = fmaf(wx0*fy*wz0,  f010.x, o0);      o1 = fmaf(wx0*fy*wz0,  f010.y, o1);
        o0 = fmaf(wx0*fy*fz,   f011.x, o0);      o1 = fmaf(wx0*fy*fz,   f011.y, o1);
        o0 = fmaf(fx*wy0*wz0,  f100.x, o0);      o1 = fmaf(fx*wy0*wz0,  f100.y, o1);
        o0 = fmaf(fx*wy0*fz,   f101.x, o0);      o1 = fmaf(fx*wy0*fz,   f101.y, o1);
        o0 = fmaf(fx*fy*wz0,   f110.x, o0);      o1 = fmaf(fx*fy*wz0,   f110.y, o1);
        o0 = fmaf(fx*fy*fz,    f111.x, o0);      o1 = fmaf(fx*fy*fz,    f111.y, o1);

        featws[(size_t)l * NPTS + p] = packbf(o0, o1);
    } else {
        // -------- oct/quad path: 4 points/thread --------
        const int g  = xcd * 224 + (s - 1152);    // 0..1791
        const int l  = g >> 8;                    // 0..6
        const int c  = g & 255;
        const int D  = qi.dim[l];
        const int DD = D*D;
        const int off = qi.off[l];
        const float r = res.r[l];

        int   pidx[4];
        uint4 qA[4], qB[4];
        float fxa[4], fya[4], fza[4];
        #pragma unroll
        for (int k = 0; k < 4; ++k) {
            const int p = c*1024 + k*256 + tid;
            pidx[k] = p;
            const float cx = coords[3*p], cy = coords[3*p+1], cz = coords[3*p+2];
            const float px = cx*r, py = cy*r, pz = cz*r;
            const float fpx = floorf(px), fpy = floorf(py), fpz = floorf(pz);
            fxa[k] = px-fpx; fya[k] = py-fpy; fza[k] = pz-fpz;
            const int ix=(int)fpx, iy=(int)fpy, iz=(int)fpz;
            const int v0 = (ix*D + iy)*D + iz;
            if (l < 6) {
                qA[k] = octq[off + 2*v0];
                qB[k] = octq[off + 2*v0 + 1];   // same 64B line -> merged
            } else {
                qA[k] = octq[off + v0];
                qB[k] = octq[off + v0 + DD];
            }
        }
        #pragma unroll
        for (int k = 0; k < 4; ++k) {
            const float fx = fxa[k], fy = fya[k], fz = fza[k];
            const float wx0=1.f-fx, wy0=1.f-fy, wz0=1.f-fz;
            const float w000=wx0*wy0*wz0, w001=wx0*wy0*fz;
            const float w010=wx0*fy*wz0,  w011=wx0*fy*fz;
            const float w100=fx*wy0*wz0,  w101=fx*wy0*fz;
            const float w110=fx*fy*wz0,   w111=fx*fy*fz;
            float o0, o1;
            o0 = w000*blo(qA[k].x);              o1 = w000*bhi(qA[k].x);
            o0 = fmaf(w001, blo(qA[k].y), o0);   o1 = fmaf(w001, bhi(qA[k].y), o1);
            o0 = fmaf(w010, blo(qA[k].z), o0);   o1 = fmaf(w010, bhi(qA[k].z), o1);
            o0 = fmaf(w011, blo(qA[k].w), o0);   o1 = fmaf(w011, bhi(qA[k].w), o1);
            o0 = fmaf(w100, blo(qB[k].x), o0);   o1 = fmaf(w100, bhi(qB[k].x), o1);
            o0 = fmaf(w101, blo(qB[k].y), o0);   o1 = fmaf(w101, bhi(qB[k].y), o1);
            o0 = fmaf(w110, blo(qB[k].z), o0);   o1 = fmaf(w110, bhi(qB[k].z), o1);
            o0 = fmaf(w111, blo(qB[k].w), o0);   o1 = fmaf(w111, bhi(qB[k].w), o1);
            featws[(size_t)l * NPTS + pidx[k]] = packbf(o0, o1);
        }
    }
}

// ---------------------------------------------------------------------------
// Kernel 2: MFMA MLP chain. 128 points/block. Weights staged via fast
// coalesced copy from the pre-packed ws image.
// ---------------------------------------------------------------------------
__global__ __launch_bounds__(256, 3) void mlp_mfma_k(
    const unsigned* __restrict__ featws,
    const unsigned short* __restrict__ wpk,
    const float* __restrict__ bpk,
    const float* __restrict__ dirs,
    float* __restrict__ out)
{
    const int tid  = threadIdx.x;
    const int wid  = tid >> 6;
    const int lane = tid & 63;
    const int m16  = lane & 15;
    const int q    = lane >> 4;

    __shared__ __align__(16) unsigned short wlds[28 * 512];
    __shared__ float blds[288];
    __shared__ __align__(16) unsigned short featL[TPB * 40];   // [pt][32+8 pad] bf16
    __shared__ __align__(16) unsigned short actL[4 * 16 * 72]; // per-wave [16][64+8] bf16

    {
        uint4* dst = (uint4*)wlds;
        const uint4* srcv = (const uint4*)wpk;   // 1792 uint4
        #pragma unroll
        for (int j = 0; j < 7; ++j) dst[j*256 + tid] = srcv[j*256 + tid];
        if (tid < 256) blds[tid] = bpk[tid];           // biases 0..255
        if (tid < 32)  blds[256 + tid] = bpk[256 + tid]; // biases 256..287 (cb3 tail + cb4)
    }

    const int pbase = blockIdx.x * TPB;
    unsigned* fL32 = (unsigned*)featL;        // row stride 20 uints
    #pragma unroll
    for (int j = 0; j < 8; ++j) {
        const int idx  = j*256 + tid;
        const int l    = idx >> 7;
        const int ploc = idx & 127;
        fL32[ploc*20 + l] = featws[(size_t)l * NPTS + pbase + ploc];
    }
    __syncthreads();

    unsigned short* aw = actL + wid*1152;     // 16 x 72
    const short8* wfr = (const short8*)wlds;  // B(s) = wfr[s*64 + lane]

    #pragma unroll
    for (int iter = 0; iter < 2; ++iter) {
        const int tile = wid + 4*iter;
        const int loc0 = tile*16;
        const int p0g  = pbase + loc0;

        // ---- density L1: feat(32) -> 64, relu ----
        short8 a0 = *(const short8*)(featL + (loc0+m16)*40 + q*8);
        f32x4 acc[4];
        #pragma unroll
        for (int nc = 0; nc < 4; ++nc) {
            const float b = blds[nc*16 + m16];
            acc[nc] = (f32x4){b,b,b,b};
            acc[nc] = MFMA(a0, wfr[nc*64 + lane], acc[nc]);
        }
        #pragma unroll
        for (int nc = 0; nc < 4; ++nc)
            #pragma unroll
            for (int r = 0; r < 4; ++r)
                aw[(q*4+r)*72 + nc*16 + m16] = f2bf(fmaxf(acc[nc][r], 0.f));

        // ---- density L2: 64 -> 16 (no act) ----
        short8 ad0 = *(const short8*)(aw + m16*72 + q*8);
        short8 ad1 = *(const short8*)(aw + m16*72 + 32 + q*8);
        f32x4 dob;
        { const float b = blds[64 + m16]; dob = (f32x4){b,b,b,b}; }
        dob = MFMA(ad0, wfr[4*64 + lane], dob);
        dob = MFMA(ad1, wfr[5*64 + lane], dob);

        if (m16 == 0) {
            #pragma unroll
            for (int r = 0; r < 4; ++r) out[p0g + q*4 + r] = expf(dob[r]);
        }

        // ---- build inp = [SH(16) | dob(16)] ----
        #pragma unroll
        for (int r = 0; r < 4; ++r)
            aw[(q*4+r)*72 + 16 + m16] = f2bf(dob[r]);
        {
            const int pg = p0g + m16;
            const float dx0 = dirs[3*pg], dy0 = dirs[3*pg+1], dz0 = dirs[3*pg+2];
            const float inv = 1.f / sqrtf(dx0*dx0 + dy0*dy0 + dz0*dz0);
            float x = dx0*inv, y = dy0*inv, z = dz0*inv;
            x = ((x+1.f)*0.5f)*2.f - 1.f;
            y = ((y+1.f)*0.5f)*2.f - 1.f;
            z = ((z+1.f)*0.5f)*2.f - 1.f;
            float s0, s1, s2, s3;
            switch (q) {
            case 0: s0 = 0.28209479177387814f;
                    s1 = -0.48860251190291987f*y;
                    s2 =  0.48860251190291987f*z;
                    s3 = -0.48860251190291987f*x; break;
            case 1: s0 =  1.0925484305920792f*x*y;
                    s1 = -1.0925484305920792f*y*z;
                    s2 =  0.94617469575756f*z*z - 0.31539156525252f;
                    s3 = -1.0925484305920792f*x*z; break;
            case 2: s0 =  0.5462742152960396f*(x*x - y*y);
                    s1 =  0.5900435899266435f*y*(-3.f*x*x + y*y);
                    s2 =  2.890611442640554f*x*y*z;
                    s3 =  0.4570457994644657f*y*(1.f - 5.f*z*z); break;
            default:s0 =  0.3731763325901154f*z*(5.f*z*z - 3.f);
                    s1 =  0.4570457994644657f*x*(1.f - 5.f*z*z);
                    s2 =  1.445305721320277f*z*(x*x - y*y);
                    s3 =  0.5900435899266435f*x*(x*x - 3.f*y*y); break;
            }
            unsigned* ip = (unsigned*)(aw + m16*72 + q*4);
            ip[0] = packbf(s0, s1);
            ip[1] = packbf(s2, s3);
        }

        // ---- color L1: inp(32) -> 64, relu ----
        short8 ac0 = *(const short8*)(aw + m16*72 + q*8);
        #pragma unroll
        for (int nc = 0; nc < 4; ++nc) {
            const float b = blds[80 + nc*16 + m16];
            acc[nc] = (f32x4){b,b,b,b};
            acc[nc] = MFMA(ac0, wfr[(6+nc)*64 + lane], acc[nc]);
        }
        #pragma unroll
        for (int nc = 0; nc < 4; ++nc)
            #pragma unroll
            for (int r = 0; r < 4; ++r)
                aw[(q*4+r)*72 + nc*16 + m16] = f2bf(fmaxf(acc[nc][r], 0.f));

        // ---- color L2: 64 -> 64, relu ----
        short8 a20 = *(const short8*)(aw + m16*72 + q*8);
        short8 a21 = *(const short8*)(aw + m16*72 + 32 + q*8);
        #pragma unroll
        for (int nc = 0; nc < 4; ++nc) {
            const float b = blds[144 + nc*16 + m16];
            acc[nc] = (f32x4){b,b,b,b};
            acc[nc] = MFMA(a20, wfr[(10+nc)*64 + lane], acc[nc]);
            acc[nc] = MFMA(a21, wfr[(14+nc)*64 + lane], acc[nc]);
        }
        #pragma unroll
        for (int nc = 0; nc < 4; ++nc)
            #pragma unroll
            for (int r = 0; r < 4; ++r)
                aw[(q*4+r)*72 + nc*16 + m16] = f2bf(fmaxf(acc[nc][r], 0.f));

        // ---- color L3: 64 -> 64, relu ----
        short8 a30 = *(const short8*)(aw + m16*72 + q*8);
        short8 a31 = *(const short8*)(aw + m16*72 + 32 + q*8);
        #pragma unroll
        for (int nc = 0; nc < 4; ++nc) {
            const float b = blds[208 + nc*16 + m16];
            acc[nc] = (f32x4){b,b,b,b};
            acc[nc] = MFMA(a30, wfr[(18+nc)*64 + lane], acc[nc]);
            acc[nc] = MFMA(a31, wfr[(22+nc)*64 + lane], acc[nc]);
        }
        #pragma unroll
        for (int nc = 0; nc < 4; ++nc)
            #pragma unroll
            for (int r = 0; r < 4; ++r)
                aw[(q*4+r)*72 + nc*16 + m16] = f2bf(fmaxf(acc[nc][r], 0.f));

        // ---- color L4: 64 -> 3 (padded to 16), sigmoid ----
        short8 a40 = *(const short8*)(aw + m16*72 + q*8);
        short8 a41 = *(const short8*)(aw + m16*72 + 32 + q*8);
        f32x4 c4;
        { const float b = blds[272 + m16]; c4 = (f32x4){b,b,b,b}; }
        c4 = MFMA(a40, wfr[26*64 + lane], c4);
        c4 = MFMA(a41, wfr[27*64 + lane], c4);
        if (m16 < 3) {
            #pragma unroll
            for (int r = 0; r < 4; ++r)
                out[NPTS + 3*(p0g + q*4 + r) + m16] = 1.f / (1.f + expf(-c4[r]));
        }
    }
}

extern "C" void kernel_launch(void* const* d_in, const int* in_sizes, int n_in,
                              void* d_out, int out_size, void* d_ws, size_t ws_size,
                              hipStream_t stream)
{
    // RES must bit-match numpy: floor(16 * b**l) in f64, b = exp((ln512-ln16)/15).
    ResArr res;
    const double b = exp((log(512.0) - log(16.0)) / 15.0);
    for (int l = 0; l < NLVL; ++l)
        res.r[l] = (float)floor(16.0 * pow(b, (double)l));

    // densified arrays: l0..5 oct (2 uint4/cell), l6 quad (1 uint4/cell)
    QuadInfo qi;
    int off = 0, maxn = 0;
    for (int l = 0; l < NQ; ++l) {
        const int D = (int)res.r[l] + 1;
        qi.dim[l] = D;
        qi.off[l] = off;
        const int n = D*D*D;
        off += (l < 6) ? 2*n : n;
        if (n > maxn) maxn = n;
    }

    // ws: featws 16.8MB | oct/quad (off*16B ~ 13.0MB) | wpk 28KB | bpk 1.2KB
    unsigned*       featws = (unsigned*)d_ws;
    uint4*          octq   = (uint4*)((char*)d_ws + (size_t)NLVL * NPTS * 4);
    unsigned short* wpk    = (unsigned short*)((char*)octq + (size_t)off * 16);
    float*          bpk    = (float*)((char*)wpk + 28 * 512 * 2);

    prep_k<<<dim3((maxn + 255)/256, 8), 256, 0, stream>>>(
        (const float*)d_in[2], octq, qi,
        (const float*)d_in[3],  (const float*)d_in[4],
        (const float*)d_in[5],  (const float*)d_in[6],
        (const float*)d_in[7],  (const float*)d_in[8],
        (const float*)d_in[9],  (const float*)d_in[10],
        (const float*)d_in[11], (const float*)d_in[12],
        (const float*)d_in[13], (const float*)d_in[14],
        wpk, bpk);

    hash_encode_k<<<11008, 256, 0, stream>>>(
        (const float*)d_in[0],   // coords
        (const float*)d_in[2],   // embeddings
        octq, featws, res, qi);

    mlp_mfma_k<<<NPTS/TPB, 256, 0, stream>>>(
        featws, wpk, bpk,
        (const float*)d_in[1],   // directions
        (float*)d_out);
}

// Round 11
// 254.214 us; speedup vs baseline: 1.0196x; 1.0196x over previous
//
#include <hip/hip_runtime.h>
#include <cmath>

#define NPTS 262144
#define NLVL 16
#define TBL  524288u
#define TMASK 524287u
#define TPB  256   // points per block (k2)
#define NQ   7     // levels 0..6 quad-densified

typedef __attribute__((ext_vector_type(8))) short short8;
typedef __attribute__((ext_vector_type(4))) float f32x4;

struct ResArr { float r[NLVL]; };
struct QuadInfo { int off[NQ]; int dim[NQ]; };   // off in uint4 units

__device__ __forceinline__ unsigned short f2bf(float f) {
    union { float f; unsigned u; } v; v.f = f;
    unsigned r = v.u + 0x7FFFu + ((v.u >> 16) & 1u);   // RNE
    return (unsigned short)(r >> 16);
}
__device__ __forceinline__ float blo(unsigned u) {
    union { unsigned v; float f; } x; x.v = u << 16; return x.f;
}
__device__ __forceinline__ float bhi(unsigned u) {
    union { unsigned v; float f; } x; x.v = u & 0xffff0000u; return x.f;
}
__device__ __forceinline__ unsigned packbf(float a, float b) {
    return (unsigned)f2bf(a) | ((unsigned)f2bf(b) << 16);
}

#define MFMA(a,b,c) __builtin_amdgcn_mfma_f32_16x16x32_bf16((a),(b),(c),0,0,0)

// ---------------------------------------------------------------------------
// Prep kernel: blockIdx.y = level 0..6 -> quad arrays
// quad[off[l]+((x*D)+y)*D+z] = uint4{c(y,z),c(y,z+1),c(y+1,z),c(y+1,z+1)} bf16.
// y==7, block 0 -> pack MLP weights + biases.
// ---------------------------------------------------------------------------
__global__ __launch_bounds__(256) void prep_k(
    const float* __restrict__ emb,
    uint4* __restrict__ quad, QuadInfo qi,
    const float* __restrict__ dw1, const float* __restrict__ db1,
    const float* __restrict__ dw2, const float* __restrict__ db2,
    const float* __restrict__ cw1, const float* __restrict__ cb1,
    const float* __restrict__ cw2, const float* __restrict__ cb2,
    const float* __restrict__ cw3, const float* __restrict__ cb3,
    const float* __restrict__ cw4, const float* __restrict__ cb4,
    unsigned short* __restrict__ wpk, float* __restrict__ bpk)
{
    const int l = blockIdx.y;
    const int tid = threadIdx.x;

    if (l == 7) {
        if (blockIdx.x != 0) return;
        const int wid  = tid >> 6;
        const int lane = tid & 63;
        const int m16  = lane & 15;
        const int q    = lane >> 4;
        const unsigned char MAT[28] = {0,0,0,0, 1,1, 2,2,2,2, 3,3,3,3,3,3,3,3, 4,4,4,4,4,4,4,4, 5,5};
        const unsigned char K0 [28] = {0,0,0,0, 0,32, 0,0,0,0, 0,0,0,0,32,32,32,32, 0,0,0,0,32,32,32,32, 0,32};
        const unsigned char N0 [28] = {0,16,32,48, 0,0, 0,16,32,48, 0,16,32,48,0,16,32,48, 0,16,32,48,0,16,32,48, 0,0};
        #pragma unroll
        for (int s = 0; s < 28; ++s) {
            if ((s & 3) == wid) {
                const int mat = MAT[s];
                const float* src = mat==0?dw1 : mat==1?dw2 : mat==2?cw1 : mat==3?cw2 : mat==4?cw3 : cw4;
                const int fan = (mat==1) ? 16 : (mat==5) ? 3 : 64;
                const int k = (int)K0[s] + q*8;
                const int n = (int)N0[s] + m16;
                unsigned short u[8];
                #pragma unroll
                for (int j = 0; j < 8; ++j) {
                    float v = 0.f;
                    if (mat != 5 || n < 3) v = src[(k+j)*fan + n];
                    u[j] = f2bf(v);
                }
                unsigned* w32 = (unsigned*)(wpk + s*512 + lane*8);
                w32[0] = (unsigned)u[0] | ((unsigned)u[1] << 16);
                w32[1] = (unsigned)u[2] | ((unsigned)u[3] << 16);
                w32[2] = (unsigned)u[4] | ((unsigned)u[5] << 16);
                w32[3] = (unsigned)u[6] | ((unsigned)u[7] << 16);
            }
        }
        {
            int t = tid;
            if      (t <  64) bpk[t] = db1[t];
            else if (t <  80) bpk[t] = db2[t-64];
            else if (t < 144) bpk[t] = cb1[t-80];
            else if (t < 208) bpk[t] = cb2[t-144];
        }
        if (tid < 80) {
            int t = tid + 208;
            if (t < 272) bpk[t] = cb3[t-208];
            else         bpk[t] = (t-272 < 3) ? cb4[t-272] : 0.f;
        }
        return;
    }

    const int t = blockIdx.x * 256 + tid;
    const int D = qi.dim[l];
    if (t >= D*D*D) return;
    const unsigned z = (unsigned)t % (unsigned)D;
    const unsigned rem = (unsigned)t / (unsigned)D;
    const unsigned y = rem % (unsigned)D;
    const unsigned x = rem / (unsigned)D;

    const float2* __restrict__ emb2 = (const float2*)emb;
    const unsigned base = (unsigned)l * TBL;
    const unsigned hy0 = y*2654435761u, hy1 = (y+1u)*2654435761u;
    const unsigned hz0 = z*805459861u,  hz1 = (z+1u)*805459861u;

    const float2 a = emb2[base + ((x^hy0^hz0)&TMASK)];
    const float2 b = emb2[base + ((x^hy0^hz1)&TMASK)];
    const float2 c = emb2[base + ((x^hy1^hz0)&TMASK)];
    const float2 d = emb2[base + ((x^hy1^hz1)&TMASK)];

    uint4 q;
    q.x = packbf(a.x, a.y);
    q.y = packbf(b.x, b.y);
    q.z = packbf(c.x, c.y);
    q.w = packbf(d.x, d.y);
    quad[qi.off[l] + t] = q;
}

// ---------------------------------------------------------------------------
// Kernel 1: hash-grid encode, cost-balanced XCD schedule (R8 config: VGPR 36).
// grid = 11008 blocks; xcd = b&7, s = b>>3 in [0,1376).
//  s < 1024        : hashed level (7+xcd), point chunk s           (2.1M/XCD)
//  1024 <= s <1152 : l15 eighth                                    (0.26M/XCD)
//  s >= 1152       : quad g = xcd*224+(s-1152): l=g>>8, c=g&255    (0.46M/XCD)
// Max per-XCD = 2.82M L2 requests; measured 102us = 88% of 13.1 req/cy floor.
// ---------------------------------------------------------------------------
__global__ __launch_bounds__(256) void hash_encode_k(
    const float* __restrict__ coords,
    const float* __restrict__ emb,
    const uint4* __restrict__ quad,
    unsigned* __restrict__ featws,
    ResArr res, QuadInfo qi)
{
    const int tid = threadIdx.x;
    const int b   = blockIdx.x;
    const int xcd = b & 7;
    const int s   = b >> 3;

    if (s < 1152) {
        // -------- hashed path --------
        int l, p;
        if (s < 1024) {
            l = 7 + xcd;
            p = s * 256 + tid;
        } else {
            l = 15;
            p = xcd * 32768 + (s - 1024) * 256 + tid;
        }

        const float cx = coords[3*p], cy = coords[3*p+1], cz = coords[3*p+2];
        const float r = res.r[l];
        const float px = cx*r, py = cy*r, pz = cz*r;
        const float fpx = floorf(px), fpy = floorf(py), fpz = floorf(pz);
        const float fx = px-fpx, fy = py-fpy, fz = pz-fpz;
        const unsigned ix=(unsigned)fpx, iy=(unsigned)fpy, iz=(unsigned)fpz;
        const unsigned hx0=ix,             hx1=ix+1u;
        const unsigned hy0=iy*2654435761u, hy1=(iy+1u)*2654435761u;
        const unsigned hz0=iz*805459861u,  hz1=(iz+1u)*805459861u;
        const unsigned base = (unsigned)l * TBL;
        const float2* __restrict__ emb2 = (const float2*)emb;

        const float2 f000 = emb2[base + ((hx0^hy0^hz0)&TMASK)];
        const float2 f001 = emb2[base + ((hx0^hy0^hz1)&TMASK)];
        const float2 f010 = emb2[base + ((hx0^hy1^hz0)&TMASK)];
        const float2 f011 = emb2[base + ((hx0^hy1^hz1)&TMASK)];
        const float2 f100 = emb2[base + ((hx1^hy0^hz0)&TMASK)];
        const float2 f101 = emb2[base + ((hx1^hy0^hz1)&TMASK)];
        const float2 f110 = emb2[base + ((hx1^hy1^hz0)&TMASK)];
        const float2 f111 = emb2[base + ((hx1^hy1^hz1)&TMASK)];

        const float wx0=1.f-fx, wy0=1.f-fy, wz0=1.f-fz;
        float o0, o1;
        o0 = wx0*wy0*wz0*f000.x;                 o1 = wx0*wy0*wz0*f000.y;
        o0 = fmaf(wx0*wy0*fz,  f001.x, o0);      o1 = fmaf(wx0*wy0*fz,  f001.y, o1);
        o0 = fmaf(wx0*fy*wz0,  f010.x, o0);      o1 = fmaf(wx0*fy*wz0,  f010.y, o1);
        o0 = fmaf(wx0*fy*fz,   f011.x, o0);      o1 = fmaf(wx0*fy*fz,   f011.y, o1);
        o0 = fmaf(fx*wy0*wz0,  f100.x, o0);      o1 = fmaf(fx*wy0*wz0,  f100.y, o1);
        o0 = fmaf(fx*wy0*fz,   f101.x, o0);      o1 = fmaf(fx*wy0*fz,   f101.y, o1);
        o0 = fmaf(fx*fy*wz0,   f110.x, o0);      o1 = fmaf(fx*fy*wz0,   f110.y, o1);
        o0 = fmaf(fx*fy*fz,    f111.x, o0);      o1 = fmaf(fx*fy*fz,    f111.y, o1);

        featws[(size_t)l * NPTS + p] = packbf(o0, o1);
    } else {
        // -------- quad path: 4 points/thread, 2 loads/point --------
        const int g  = xcd * 224 + (s - 1152);    // 0..1791
        const int l  = g >> 8;                    // 0..6
        const int c  = g & 255;
        const int D  = qi.dim[l];
        const int DD = D*D;
        const int off = qi.off[l];
        const float r = res.r[l];

        int   pidx[4];
        uint4 qA[4], qB[4];
        float fxa[4], fya[4], fza[4];
        #pragma unroll
        for (int k = 0; k < 4; ++k) {
            const int p = c*1024 + k*256 + tid;
            pidx[k] = p;
            const float cx = coords[3*p], cy = coords[3*p+1], cz = coords[3*p+2];
            const float px = cx*r, py = cy*r, pz = cz*r;
            const float fpx = floorf(px), fpy = floorf(py), fpz = floorf(pz);
            fxa[k] = px-fpx; fya[k] = py-fpy; fza[k] = pz-fpz;
            const int ix=(int)fpx, iy=(int)fpy, iz=(int)fpz;
            const int v0 = off + (ix*D + iy)*D + iz;
            qA[k] = quad[v0];
            qB[k] = quad[v0 + DD];
        }
        #pragma unroll
        for (int k = 0; k < 4; ++k) {
            const float fx = fxa[k], fy = fya[k], fz = fza[k];
            const float wx0=1.f-fx, wy0=1.f-fy, wz0=1.f-fz;
            const float w000=wx0*wy0*wz0, w001=wx0*wy0*fz;
            const float w010=wx0*fy*wz0,  w011=wx0*fy*fz;
            const float w100=fx*wy0*wz0,  w101=fx*wy0*fz;
            const float w110=fx*fy*wz0,   w111=fx*fy*fz;
            float o0, o1;
            o0 = w000*blo(qA[k].x);              o1 = w000*bhi(qA[k].x);
            o0 = fmaf(w001, blo(qA[k].y), o0);   o1 = fmaf(w001, bhi(qA[k].y), o1);
            o0 = fmaf(w010, blo(qA[k].z), o0);   o1 = fmaf(w010, bhi(qA[k].z), o1);
            o0 = fmaf(w011, blo(qA[k].w), o0);   o1 = fmaf(w011, bhi(qA[k].w), o1);
            o0 = fmaf(w100, blo(qB[k].x), o0);   o1 = fmaf(w100, bhi(qB[k].x), o1);
            o0 = fmaf(w101, blo(qB[k].y), o0);   o1 = fmaf(w101, bhi(qB[k].y), o1);
            o0 = fmaf(w110, blo(qB[k].z), o0);   o1 = fmaf(w110, bhi(qB[k].z), o1);
            o0 = fmaf(w111, blo(qB[k].w), o0);   o1 = fmaf(w111, bhi(qB[k].w), o1);
            featws[(size_t)l * NPTS + pidx[k]] = packbf(o0, o1);
        }
    }
}

// ---------------------------------------------------------------------------
// Kernel 2: MFMA MLP chain. 256 points/block (1024 blocks -> half the
// weight-image re-reads vs TPB=128). LDS ~59KB -> 2 blocks/CU.
// ---------------------------------------------------------------------------
__global__ __launch_bounds__(256, 2) void mlp_mfma_k(
    const unsigned* __restrict__ featws,
    const unsigned short* __restrict__ wpk,
    const float* __restrict__ bpk,
    const float* __restrict__ dirs,
    float* __restrict__ out)
{
    const int tid  = threadIdx.x;
    const int wid  = tid >> 6;
    const int lane = tid & 63;
    const int m16  = lane & 15;
    const int q    = lane >> 4;

    __shared__ __align__(16) unsigned short wlds[28 * 512];
    __shared__ float blds[288];
    __shared__ __align__(16) unsigned short featL[TPB * 40];   // [pt][32+8 pad] bf16
    __shared__ __align__(16) unsigned short actL[4 * 16 * 72]; // per-wave [16][64+8] bf16

    {
        uint4* dst = (uint4*)wlds;
        const uint4* srcv = (const uint4*)wpk;   // 1792 uint4
        #pragma unroll
        for (int j = 0; j < 7; ++j) dst[j*256 + tid] = srcv[j*256 + tid];
        if (tid < 256) blds[tid] = bpk[tid];             // biases 0..255
        if (tid < 32)  blds[256 + tid] = bpk[256 + tid]; // 256..287 (cb3 tail + cb4)
    }

    const int pbase = blockIdx.x * TPB;
    unsigned* fL32 = (unsigned*)featL;        // row stride 20 uints
    #pragma unroll
    for (int j = 0; j < 16; ++j) {
        const int idx  = j*256 + tid;         // 0..4095
        const int l    = idx >> 8;
        const int ploc = idx & 255;
        fL32[ploc*20 + l] = featws[(size_t)l * NPTS + pbase + ploc];
    }
    __syncthreads();

    unsigned short* aw = actL + wid*1152;     // 16 x 72
    const short8* wfr = (const short8*)wlds;  // B(s) = wfr[s*64 + lane]

    #pragma unroll
    for (int iter = 0; iter < 4; ++iter) {
        const int tile = wid + 4*iter;
        const int loc0 = tile*16;
        const int p0g  = pbase + loc0;

        // ---- density L1: feat(32) -> 64, relu ----
        short8 a0 = *(const short8*)(featL + (loc0+m16)*40 + q*8);
        f32x4 acc[4];
        #pragma unroll
        for (int nc = 0; nc < 4; ++nc) {
            const float b = blds[nc*16 + m16];
            acc[nc] = (f32x4){b,b,b,b};
            acc[nc] = MFMA(a0, wfr[nc*64 + lane], acc[nc]);
        }
        #pragma unroll
        for (int nc = 0; nc < 4; ++nc)
            #pragma unroll
            for (int r = 0; r < 4; ++r)
                aw[(q*4+r)*72 + nc*16 + m16] = f2bf(fmaxf(acc[nc][r], 0.f));

        // ---- density L2: 64 -> 16 (no act) ----
        short8 ad0 = *(const short8*)(aw + m16*72 + q*8);
        short8 ad1 = *(const short8*)(aw + m16*72 + 32 + q*8);
        f32x4 dob;
        { const float b = blds[64 + m16]; dob = (f32x4){b,b,b,b}; }
        dob = MFMA(ad0, wfr[4*64 + lane], dob);
        dob = MFMA(ad1, wfr[5*64 + lane], dob);

        if (m16 == 0) {
            #pragma unroll
            for (int r = 0; r < 4; ++r) out[p0g + q*4 + r] = expf(dob[r]);
        }

        // ---- build inp = [SH(16) | dob(16)] ----
        #pragma unroll
        for (int r = 0; r < 4; ++r)
            aw[(q*4+r)*72 + 16 + m16] = f2bf(dob[r]);
        {
            const int pg = p0g + m16;
            const float dx0 = dirs[3*pg], dy0 = dirs[3*pg+1], dz0 = dirs[3*pg+2];
            const float inv = 1.f / sqrtf(dx0*dx0 + dy0*dy0 + dz0*dz0);
            float x = dx0*inv, y = dy0*inv, z = dz0*inv;
            x = ((x+1.f)*0.5f)*2.f - 1.f;
            y = ((y+1.f)*0.5f)*2.f - 1.f;
            z = ((z+1.f)*0.5f)*2.f - 1.f;
            float s0, s1, s2, s3;
            switch (q) {
            case 0: s0 = 0.28209479177387814f;
                    s1 = -0.48860251190291987f*y;
                    s2 =  0.48860251190291987f*z;
                    s3 = -0.48860251190291987f*x; break;
            case 1: s0 =  1.0925484305920792f*x*y;
                    s1 = -1.0925484305920792f*y*z;
                    s2 =  0.94617469575756f*z*z - 0.31539156525252f;
                    s3 = -1.0925484305920792f*x*z; break;
            case 2: s0 =  0.5462742152960396f*(x*x - y*y);
                    s1 =  0.5900435899266435f*y*(-3.f*x*x + y*y);
                    s2 =  2.890611442640554f*x*y*z;
                    s3 =  0.4570457994644657f*y*(1.f - 5.f*z*z); break;
            default:s0 =  0.3731763325901154f*z*(5.f*z*z - 3.f);
                    s1 =  0.4570457994644657f*x*(1.f - 5.f*z*z);
                    s2 =  1.445305721320277f*z*(x*x - y*y);
                    s3 =  0.5900435899266435f*x*(x*x - 3.f*y*y); break;
            }
            unsigned* ip = (unsigned*)(aw + m16*72 + q*4);
            ip[0] = packbf(s0, s1);
            ip[1] = packbf(s2, s3);
        }

        // ---- color L1: inp(32) -> 64, relu ----
        short8 ac0 = *(const short8*)(aw + m16*72 + q*8);
        #pragma unroll
        for (int nc = 0; nc < 4; ++nc) {
            const float b = blds[80 + nc*16 + m16];
            acc[nc] = (f32x4){b,b,b,b};
            acc[nc] = MFMA(ac0, wfr[(6+nc)*64 + lane], acc[nc]);
        }
        #pragma unroll
        for (int nc = 0; nc < 4; ++nc)
            #pragma unroll
            for (int r = 0; r < 4; ++r)
                aw[(q*4+r)*72 + nc*16 + m16] = f2bf(fmaxf(acc[nc][r], 0.f));

        // ---- color L2: 64 -> 64, relu ----
        short8 a20 = *(const short8*)(aw + m16*72 + q*8);
        short8 a21 = *(const short8*)(aw + m16*72 + 32 + q*8);
        #pragma unroll
        for (int nc = 0; nc < 4; ++nc) {
            const float b = blds[144 + nc*16 + m16];
            acc[nc] = (f32x4){b,b,b,b};
            acc[nc] = MFMA(a20, wfr[(10+nc)*64 + lane], acc[nc]);
            acc[nc] = MFMA(a21, wfr[(14+nc)*64 + lane], acc[nc]);
        }
        #pragma unroll
        for (int nc = 0; nc < 4; ++nc)
            #pragma unroll
            for (int r = 0; r < 4; ++r)
                aw[(q*4+r)*72 + nc*16 + m16] = f2bf(fmaxf(acc[nc][r], 0.f));

        // ---- color L3: 64 -> 64, relu ----
        short8 a30 = *(const short8*)(aw + m16*72 + q*8);
        short8 a31 = *(const short8*)(aw + m16*72 + 32 + q*8);
        #pragma unroll
        for (int nc = 0; nc < 4; ++nc) {
            const float b = blds[208 + nc*16 + m16];
            acc[nc] = (f32x4){b,b,b,b};
            acc[nc] = MFMA(a30, wfr[(18+nc)*64 + lane], acc[nc]);
            acc[nc] = MFMA(a31, wfr[(22+nc)*64 + lane], acc[nc]);
        }
        #pragma unroll
        for (int nc = 0; nc < 4; ++nc)
            #pragma unroll
            for (int r = 0; r < 4; ++r)
                aw[(q*4+r)*72 + nc*16 + m16] = f2bf(fmaxf(acc[nc][r], 0.f));

        // ---- color L4: 64 -> 3 (padded to 16), sigmoid ----
        short8 a40 = *(const short8*)(aw + m16*72 + q*8);
        short8 a41 = *(const short8*)(aw + m16*72 + 32 + q*8);
        f32x4 c4;
        { const float b = blds[272 + m16]; c4 = (f32x4){b,b,b,b}; }
        c4 = MFMA(a40, wfr[26*64 + lane], c4);
        c4 = MFMA(a41, wfr[27*64 + lane], c4);
        if (m16 < 3) {
            #pragma unroll
            for (int r = 0; r < 4; ++r)
                out[NPTS + 3*(p0g + q*4 + r) + m16] = 1.f / (1.f + expf(-c4[r]));
        }
    }
}

extern "C" void kernel_launch(void* const* d_in, const int* in_sizes, int n_in,
                              void* d_out, int out_size, void* d_ws, size_t ws_size,
                              hipStream_t stream)
{
    // RES must bit-match numpy: floor(16 * b**l) in f64, b = exp((ln512-ln16)/15).
    ResArr res;
    const double b = exp((log(512.0) - log(16.0)) / 15.0);
    for (int l = 0; l < NLVL; ++l)
        res.r[l] = (float)floor(16.0 * pow(b, (double)l));

    // quad arrays for levels 0..6: dim = res+1
    QuadInfo qi;
    int off = 0, maxn = 0;
    for (int l = 0; l < NQ; ++l) {
        const int D = (int)res.r[l] + 1;
        qi.dim[l] = D;
        qi.off[l] = off;
        off += D*D*D;
        if (D*D*D > maxn) maxn = D*D*D;
    }

    // ws: featws 16.8MB | quads (543,884*16B = 8.7MB) | wpk 28KB | bpk 1.2KB
    unsigned*       featws = (unsigned*)d_ws;
    uint4*          quad   = (uint4*)((char*)d_ws + (size_t)NLVL * NPTS * 4);
    unsigned short* wpk    = (unsigned short*)((char*)quad + (size_t)off * 16);
    float*          bpk    = (float*)((char*)wpk + 28 * 512 * 2);

    prep_k<<<dim3((maxn + 255)/256, 8), 256, 0, stream>>>(
        (const float*)d_in[2], quad, qi,
        (const float*)d_in[3],  (const float*)d_in[4],
        (const float*)d_in[5],  (const float*)d_in[6],
        (const float*)d_in[7],  (const float*)d_in[8],
        (const float*)d_in[9],  (const float*)d_in[10],
        (const float*)d_in[11], (const float*)d_in[12],
        (const float*)d_in[13], (const float*)d_in[14],
        wpk, bpk);

    hash_encode_k<<<11008, 256, 0, stream>>>(
        (const float*)d_in[0],   // coords
        (const float*)d_in[2],   // embeddings
        quad, featws, res, qi);

    mlp_mfma_k<<<NPTS/TPB, 256, 0, stream>>>(
        featws, wpk, bpk,
        (const float*)d_in[1],   // directions
        (float*)d_out);
}